// Round 8
// baseline (819.808 us; speedup 1.0000x reference)
//
#include <hip/hip_runtime.h>

#define NN 100000
#define NE 3200000
#define HM 30
#define HG 10
#define MAXK 26
#define OVF_CAP 8192
#define RCAP 65536
#define TAU 0.01f

typedef __bf16 bf16x8 __attribute__((ext_vector_type(8)));
typedef float floatx4 __attribute__((ext_vector_type(4)));

#define LDS_SYNC() asm volatile("s_waitcnt lgkmcnt(0)" ::: "memory")

// ---------------- Stage 0: pack node features + xw ----------------
__global__ __launch_bounds__(256) void pack_kernel(
    const float* __restrict__ x, const float* __restrict__ token,
    const float* __restrict__ Wc,
    float* __restrict__ xall8, float* __restrict__ xwp)
{
    int n = blockIdx.x * 256 + threadIdx.x;
    if (n >= NN) return;

    float xa[6];
    xa[0] = x[n];
    #pragma unroll
    for (int i = 0; i < 5; i++) xa[1 + i] = token[n * 5 + i];

    float4* x4 = (float4*)xall8;
    x4[n * 2 + 0] = make_float4(xa[0], xa[1], xa[2], xa[3]);
    x4[n * 2 + 1] = make_float4(xa[4], xa[5], 0.f, 0.f);

    float w[12];
    #pragma unroll
    for (int k = 0; k < HG; k++) {
        float a = 0.f;
        #pragma unroll
        for (int i = 0; i < 6; i++) a = fmaf(xa[i], Wc[i * HG + k], a);
        w[k] = a;
    }
    w[10] = 0.f; w[11] = 0.f;
    float4* wp = (float4*)(xwp + (size_t)n * 12);
    wp[0] = make_float4(w[0], w[1], w[2], w[3]);
    wp[1] = make_float4(w[4], w[5], w[6], w[7]);
    wp[2] = make_float4(w[8], w[9], w[10], w[11]);
}

// ---------------- Stage 1: MFMA edge MLP + near-tie capture -----------------
// Wave handles 16 edges. Weights as bf16 B-fragments in VGPRs (no LDS bytes
// per edge for weights — R2/R3/R7 all plateaued at the 9 KB/edge LDS-byte
// wall). fp32-exact decisions via |margin|<=TAU recheck list.
// Layouts (HW-verified): A[m=lane&15][k=quad*8+j]; C/D[col=lane&15][row=quad*4+reg].
__global__ __launch_bounds__(256) void edge_mfma_kernel(
    const float* __restrict__ xall8,
    const float* __restrict__ eg, const float* __restrict__ ee,
    const float* __restrict__ gum, const int* __restrict__ eidx,
    const float* __restrict__ W0, const float* __restrict__ b0,
    const float* __restrict__ W1, const float* __restrict__ b1,
    const float* __restrict__ W2, const float* __restrict__ b2,
    const float* __restrict__ W3, const float* __restrict__ b3,
    const float* __restrict__ Wl, const float* __restrict__ bl,
    float* __restrict__ slots_w, int* __restrict__ slots_s,
    int* __restrict__ cnt,
    int* __restrict__ ohead, int* __restrict__ onxt,
    float* __restrict__ ovf_w, int* __restrict__ ovf_s, int* __restrict__ novf,
    int* __restrict__ rid, int* __restrict__ ncheck)
{
    __shared__ __bf16 sT[4][16][40];   // per-wave transform buffer (pad 40 vs bank alias)
    __shared__ float  sL[4][16][2];    // per-wave final logits

    const int tid  = threadIdx.x;
    const int w    = tid >> 6;
    const int lane = tid & 63;
    const int quad = lane >> 4;
    const int r    = lane & 15;
    const int base = blockIdx.x * 64 + w * 16;   // 3.2M/64 = 50000 blocks exactly

    // ---- B-fragments (weights) in VGPRs: frag[j] = W[k=quad*8+j][col] ----
    bf16x8 B0a, B0b, B1a, B1b, B2a, B2b, B3f;
    {
        const int c0 = r, c1 = 16 + r;
        #pragma unroll
        for (int j = 0; j < 8; j++) {
            int k = quad * 8 + j;
            B0a[j] = (k < 13)            ? (__bf16)W0[k * HM + c0] : (__bf16)0.f;
            B0b[j] = (k < 13 && c1 < HM) ? (__bf16)W0[k * HM + c1] : (__bf16)0.f;
            B1a[j] = (k < HM)            ? (__bf16)W1[k * HM + c0] : (__bf16)0.f;
            B1b[j] = (k < HM && c1 < HM) ? (__bf16)W1[k * HM + c1] : (__bf16)0.f;
            B2a[j] = (k < HM)            ? (__bf16)W2[k * HM + c0] : (__bf16)0.f;
            B2b[j] = (k < HM && c1 < HM) ? (__bf16)W2[k * HM + c1] : (__bf16)0.f;
            B3f[j] = (k < HM && c0 < 2)  ? (__bf16)W3[k * 2 + c0]  : (__bf16)0.f;
        }
    }

    // ---- Load features, build layer-0 A-fragment in registers ----
    int s = 0, t = 0;
    bf16x8 a;
    #pragma unroll
    for (int j = 0; j < 8; j++) a[j] = (__bf16)0.f;
    if (quad < 2) {
        int e = base + r;
        t = eidx[NE + e];
        const float4* x4 = (const float4*)xall8;
        if (quad == 0) {
            s = eidx[e];
            float4 qa = x4[s * 2], qb = x4[s * 2 + 1], qc = x4[t * 2];
            a[0] = (__bf16)qa.x; a[1] = (__bf16)qa.y; a[2] = (__bf16)qa.z; a[3] = (__bf16)qa.w;
            a[4] = (__bf16)qb.x; a[5] = (__bf16)qb.y; a[6] = (__bf16)qc.x; a[7] = (__bf16)qc.y;
        } else {
            float4 qc = x4[t * 2], qd = x4[t * 2 + 1];
            float egv = eg[e];
            a[0] = (__bf16)qc.z; a[1] = (__bf16)qc.w; a[2] = (__bf16)qd.x; a[3] = (__bf16)qd.y;
            a[4] = (__bf16)egv;
        }
    }

    const int c1 = 16 + r;

    // ---- Layer 0 ----
    {
        float bb0 = b0[r];
        float bb1 = (c1 < HM) ? b0[c1] : 0.f;
        floatx4 acc0 = {bb0, bb0, bb0, bb0};
        floatx4 acc1 = {bb1, bb1, bb1, bb1};
        acc0 = __builtin_amdgcn_mfma_f32_16x16x32_bf16(a, B0a, acc0, 0, 0, 0);
        acc1 = __builtin_amdgcn_mfma_f32_16x16x32_bf16(a, B0b, acc1, 0, 0, 0);
        #pragma unroll
        for (int reg = 0; reg < 4; reg++) {
            int row = quad * 4 + reg;
            sT[w][row][r]      = (__bf16)fmaxf(acc0[reg], 0.f);
            sT[w][row][16 + r] = (__bf16)fmaxf(acc1[reg], 0.f);
        }
        LDS_SYNC();
        a = *(const bf16x8*)&sT[w][r][quad * 8];
    }
    // ---- Layer 1 ----
    {
        float bb0 = b1[r];
        float bb1 = (c1 < HM) ? b1[c1] : 0.f;
        floatx4 acc0 = {bb0, bb0, bb0, bb0};
        floatx4 acc1 = {bb1, bb1, bb1, bb1};
        acc0 = __builtin_amdgcn_mfma_f32_16x16x32_bf16(a, B1a, acc0, 0, 0, 0);
        acc1 = __builtin_amdgcn_mfma_f32_16x16x32_bf16(a, B1b, acc1, 0, 0, 0);
        LDS_SYNC();   // ensure all prior A-reads done before overwrite
        #pragma unroll
        for (int reg = 0; reg < 4; reg++) {
            int row = quad * 4 + reg;
            sT[w][row][r]      = (__bf16)fmaxf(acc0[reg], 0.f);
            sT[w][row][16 + r] = (__bf16)fmaxf(acc1[reg], 0.f);
        }
        LDS_SYNC();
        a = *(const bf16x8*)&sT[w][r][quad * 8];
    }
    // ---- Layer 2 ----
    {
        float bb0 = b2[r];
        float bb1 = (c1 < HM) ? b2[c1] : 0.f;
        floatx4 acc0 = {bb0, bb0, bb0, bb0};
        floatx4 acc1 = {bb1, bb1, bb1, bb1};
        acc0 = __builtin_amdgcn_mfma_f32_16x16x32_bf16(a, B2a, acc0, 0, 0, 0);
        acc1 = __builtin_amdgcn_mfma_f32_16x16x32_bf16(a, B2b, acc1, 0, 0, 0);
        LDS_SYNC();
        #pragma unroll
        for (int reg = 0; reg < 4; reg++) {
            int row = quad * 4 + reg;
            sT[w][row][r]      = (__bf16)fmaxf(acc0[reg], 0.f);
            sT[w][row][16 + r] = (__bf16)fmaxf(acc1[reg], 0.f);
        }
        LDS_SYNC();
        a = *(const bf16x8*)&sT[w][r][quad * 8];
    }
    // ---- Layer 3 (N=2) ----
    {
        float bb = (r < 2) ? b3[r] : 0.f;
        floatx4 acc = {bb, bb, bb, bb};
        acc = __builtin_amdgcn_mfma_f32_16x16x32_bf16(a, B3f, acc, 0, 0, 0);
        if (r < 2) {
            #pragma unroll
            for (int reg = 0; reg < 4; reg++)
                sL[w][quad * 4 + reg][r] = acc[reg];
        }
        LDS_SYNC();
    }

    // ---- Decision (lanes 0-15 own one edge each) ----
    if (quad == 0) {
        int e = base + r;
        float l0 = sL[w][r][0], l1 = sL[w][r][1];
        const float2 g = ((const float2*)gum)[e];
        float margin = (l0 + g.x) - (l1 + g.y);   // active iff margin >= 0 (exact)
        if (margin > TAU) {
            const float2 e2 = ((const float2*)ee)[e];
            float z = fmaf(e2.x, Wl[0], bl[0]);
            float ew = e2.y / (1.f + __expf(-z));
            if (ew != 0.f) {
                int slot = atomicAdd(&cnt[t], 1);
                if (slot < MAXK) {
                    size_t p = (size_t)t * MAXK + slot;
                    slots_w[p] = ew;
                    slots_s[p] = s;
                } else {
                    int i = atomicAdd(novf, 1);
                    if (i < OVF_CAP) {
                        ovf_w[i] = ew; ovf_s[i] = s;
                        onxt[i] = atomicExch(&ohead[t], i);
                    }
                }
            }
        } else if (margin >= -TAU) {
            int i = atomicAdd(ncheck, 1);
            if (i < RCAP) rid[i] = e;
        }
    }
}

// ---------------- Stage 1b: exact fp32 recheck of near-tie edges ------------
// ~16k edges expected (|margin|<=0.01, logistic density 0.25). R7-proven body.
__global__ __launch_bounds__(256) void recheck_kernel(
    const float* __restrict__ xall8,
    const float* __restrict__ eg, const float* __restrict__ ee,
    const float* __restrict__ gum, const int* __restrict__ eidx,
    const float* __restrict__ W0, const float* __restrict__ b0,
    const float* __restrict__ W1, const float* __restrict__ b1,
    const float* __restrict__ W2, const float* __restrict__ b2,
    const float* __restrict__ W3, const float* __restrict__ b3,
    const float* __restrict__ Wl, const float* __restrict__ bl,
    float* __restrict__ slots_w, int* __restrict__ slots_s,
    int* __restrict__ cnt,
    int* __restrict__ ohead, int* __restrict__ onxt,
    float* __restrict__ ovf_w, int* __restrict__ ovf_s, int* __restrict__ novf,
    const int* __restrict__ rid, const int* __restrict__ ncheck)
{
    __shared__ float2 sW0p[15 * 13];
    __shared__ float2 sW1p[15 * 30];
    __shared__ float2 sW2p[15 * 30];
    __shared__ float2 sW3[HM];
    __shared__ float2 sb0p[15], sb1p[15], sb2p[15];
    __shared__ float sb3[2], sWl, sbl;

    for (int idx = threadIdx.x; idx < 15 * 13; idx += 256) {
        int jp = idx / 13, i = idx - jp * 13;
        sW0p[idx] = make_float2(W0[i * HM + 2 * jp], W0[i * HM + 2 * jp + 1]);
    }
    for (int idx = threadIdx.x; idx < 15 * 30; idx += 256) {
        int jp = idx / 30, i = idx - jp * 30;
        sW1p[idx] = make_float2(W1[i * HM + 2 * jp], W1[i * HM + 2 * jp + 1]);
        sW2p[idx] = make_float2(W2[i * HM + 2 * jp], W2[i * HM + 2 * jp + 1]);
    }
    if (threadIdx.x < HM) sW3[threadIdx.x] = ((const float2*)W3)[threadIdx.x];
    if (threadIdx.x < 15) {
        int j = threadIdx.x;
        sb0p[j] = make_float2(b0[2 * j], b0[2 * j + 1]);
        sb1p[j] = make_float2(b1[2 * j], b1[2 * j + 1]);
        sb2p[j] = make_float2(b2[2 * j], b2[2 * j + 1]);
    }
    if (threadIdx.x == 0) { sb3[0] = b3[0]; sb3[1] = b3[1]; sWl = Wl[0]; sbl = bl[0]; }
    __syncthreads();

    int i0 = blockIdx.x * 256 + threadIdx.x;
    int nc = *ncheck;
    if (nc > RCAP) nc = RCAP;
    if (i0 >= nc) return;

    int e = rid[i0];
    int s = eidx[e];
    int t = eidx[NE + e];

    const float4* x4 = (const float4*)xall8;
    float4 qa = x4[s * 2], qb = x4[s * 2 + 1];
    float4 qc = x4[t * 2], qd = x4[t * 2 + 1];
    float ef[13] = { qa.x, qa.y, qa.z, qa.w, qb.x, qb.y,
                     qc.x, qc.y, qc.z, qc.w, qd.x, qd.y, eg[e] };

    float h[HM], h2[HM];
    #pragma unroll
    for (int jp = 0; jp < 15; jp++) {
        float a0 = sb0p[jp].x, a1 = sb0p[jp].y;
        #pragma unroll
        for (int i = 0; i < 13; i++) {
            float2 w = sW0p[jp * 13 + i];
            a0 = fmaf(ef[i], w.x, a0);
            a1 = fmaf(ef[i], w.y, a1);
        }
        h[2 * jp] = fmaxf(a0, 0.f);
        h[2 * jp + 1] = fmaxf(a1, 0.f);
    }
    #pragma unroll
    for (int jp = 0; jp < 15; jp++) {
        float a0 = sb1p[jp].x, a1 = sb1p[jp].y;
        #pragma unroll
        for (int i = 0; i < HM; i++) {
            float2 w = sW1p[jp * 30 + i];
            a0 = fmaf(h[i], w.x, a0);
            a1 = fmaf(h[i], w.y, a1);
        }
        h2[2 * jp] = fmaxf(a0, 0.f);
        h2[2 * jp + 1] = fmaxf(a1, 0.f);
    }
    #pragma unroll
    for (int jp = 0; jp < 15; jp++) {
        float a0 = sb2p[jp].x, a1 = sb2p[jp].y;
        #pragma unroll
        for (int i = 0; i < HM; i++) {
            float2 w = sW2p[jp * 30 + i];
            a0 = fmaf(h2[i], w.x, a0);
            a1 = fmaf(h2[i], w.y, a1);
        }
        h[2 * jp] = fmaxf(a0, 0.f);
        h[2 * jp + 1] = fmaxf(a1, 0.f);
    }
    float l0 = sb3[0], l1 = sb3[1];
    #pragma unroll
    for (int i = 0; i < HM; i++) {
        float2 w = sW3[i];
        l0 = fmaf(h[i], w.x, l0);
        l1 = fmaf(h[i], w.y, l1);
    }

    const float2 g2 = ((const float2*)gum)[e];
    float v0 = l0 + g2.x;
    float v1 = l1 + g2.y;

    if (!(v1 > v0)) {   // exact reference condition
        const float2 e2 = ((const float2*)ee)[e];
        float z = fmaf(e2.x, sWl, sbl);
        float ew = e2.y / (1.f + __expf(-z));
        if (ew != 0.f) {
            int slot = atomicAdd(&cnt[t], 1);
            if (slot < MAXK) {
                size_t p = (size_t)t * MAXK + slot;
                slots_w[p] = ew;
                slots_s[p] = s;
            } else {
                int i = atomicAdd(novf, 1);
                if (i < OVF_CAP) {
                    ovf_w[i] = ew; ovf_s[i] = s;
                    onxt[i] = atomicExch(&ohead[t], i);
                }
            }
        }
    }
}

// ---------------- Stage 2: per-node deg from slots -> dis; scale xwp -------
__global__ __launch_bounds__(256) void node_deg_kernel(
    const float* __restrict__ slots_w, const int* __restrict__ cnt,
    const int* __restrict__ ohead, const int* __restrict__ onxt,
    const float* __restrict__ ovf_w,
    float* __restrict__ xwp, float* __restrict__ dis)
{
    int n = blockIdx.x * 256 + threadIdx.x;
    if (n >= NN) return;

    int c = cnt[n];
    int cc = c < MAXK ? c : MAXK;
    float deg = 0.f;
    for (int j = 0; j < cc; j++) deg += slots_w[(size_t)n * MAXK + j];
    for (int i = ohead[n]; i >= 0; i = onxt[i]) deg += ovf_w[i];

    float d = rsqrtf(deg + 1.0f);   // +1 = self loop
    dis[n] = d;

    float4* wp = (float4*)(xwp + (size_t)n * 12);
    #pragma unroll
    for (int q = 0; q < 3; q++) {
        float4 v = wp[q];
        v.x *= d; v.y *= d; v.z *= d; v.w *= d;
        wp[q] = v;
    }
}

// ---------------- Stage 3: per-node gather + epilogue (no atomics) ----------
__global__ __launch_bounds__(256) void gather_out2_kernel(
    const float* __restrict__ slots_w, const int* __restrict__ slots_s,
    const int* __restrict__ cnt,
    const int* __restrict__ ohead, const int* __restrict__ onxt,
    const float* __restrict__ ovf_w, const int* __restrict__ ovf_s,
    const float* __restrict__ z, const float* __restrict__ dis,
    const float* __restrict__ bc, const float* __restrict__ Wo,
    const float* __restrict__ bo, float* __restrict__ out)
{
    int n = blockIdx.x * 256 + threadIdx.x;
    if (n >= NN) return;

    const float4* Z = (const float4*)z;
    float4 A0 = make_float4(0.f, 0.f, 0.f, 0.f), A1 = A0, A2 = A0;

    int c = cnt[n];
    int cc = c < MAXK ? c : MAXK;
    for (int j = 0; j < cc; j++) {
        size_t p = (size_t)n * MAXK + j;
        float w = slots_w[p];
        int s = slots_s[p];
        float4 z0 = Z[s * 3], z1 = Z[s * 3 + 1], z2 = Z[s * 3 + 2];
        A0.x = fmaf(w, z0.x, A0.x); A0.y = fmaf(w, z0.y, A0.y);
        A0.z = fmaf(w, z0.z, A0.z); A0.w = fmaf(w, z0.w, A0.w);
        A1.x = fmaf(w, z1.x, A1.x); A1.y = fmaf(w, z1.y, A1.y);
        A1.z = fmaf(w, z1.z, A1.z); A1.w = fmaf(w, z1.w, A1.w);
        A2.x = fmaf(w, z2.x, A2.x); A2.y = fmaf(w, z2.y, A2.y);
    }
    for (int i = ohead[n]; i >= 0; i = onxt[i]) {
        float w = ovf_w[i];
        int s = ovf_s[i];
        float4 z0 = Z[s * 3], z1 = Z[s * 3 + 1], z2 = Z[s * 3 + 2];
        A0.x = fmaf(w, z0.x, A0.x); A0.y = fmaf(w, z0.y, A0.y);
        A0.z = fmaf(w, z0.z, A0.z); A0.w = fmaf(w, z0.w, A0.w);
        A1.x = fmaf(w, z1.x, A1.x); A1.y = fmaf(w, z1.y, A1.y);
        A1.z = fmaf(w, z1.z, A1.z); A1.w = fmaf(w, z1.w, A1.w);
        A2.x = fmaf(w, z2.x, A2.x); A2.y = fmaf(w, z2.y, A2.y);
    }

    float4 s0 = Z[n * 3], s1 = Z[n * 3 + 1], s2 = Z[n * 3 + 2];
    A0.x += s0.x; A0.y += s0.y; A0.z += s0.z; A0.w += s0.w;
    A1.x += s1.x; A1.y += s1.y; A1.z += s1.z; A1.w += s1.w;
    A2.x += s2.x; A2.y += s2.y;

    float d = dis[n];
    float v[10] = { A0.x, A0.y, A0.z, A0.w, A1.x, A1.y, A1.z, A1.w, A2.x, A2.y };
    float o = bo[0];
    #pragma unroll
    for (int k = 0; k < HG; k++)
        o = fmaf(fmaf(v[k], d, bc[k]), Wo[k], o);
    out[n] = 1.f / (1.f + __expf(-o));
}

// ================= Fallback path (Round-1 scatter; unused when ws fits) =====
__global__ __launch_bounds__(256) void edge_mlp_kernel(
    const float* __restrict__ x, const float* __restrict__ token,
    const float* __restrict__ eg, const float* __restrict__ ee,
    const float* __restrict__ gum, const int* __restrict__ eidx,
    const float* __restrict__ W0, const float* __restrict__ b0,
    const float* __restrict__ W1, const float* __restrict__ b1,
    const float* __restrict__ W2, const float* __restrict__ b2,
    const float* __restrict__ W3, const float* __restrict__ b3,
    const float* __restrict__ Wl, const float* __restrict__ bl,
    float* __restrict__ ew_out, float* __restrict__ deg)
{
    int e = blockIdx.x * 256 + threadIdx.x;
    if (e >= NE) return;
    int s = eidx[e];
    int t = eidx[NE + e];

    float ef[13];
    ef[0] = x[s];
    #pragma unroll
    for (int i = 0; i < 5; i++) ef[1 + i] = token[s * 5 + i];
    ef[6] = x[t];
    #pragma unroll
    for (int i = 0; i < 5; i++) ef[7 + i] = token[t * 5 + i];
    ef[12] = eg[e];

    float h[HM], h2[HM];
    #pragma unroll
    for (int j = 0; j < HM; j++) {
        float a = b0[j];
        #pragma unroll
        for (int i = 0; i < 13; i++) a = fmaf(ef[i], W0[i * HM + j], a);
        h[j] = fmaxf(a, 0.f);
    }
    #pragma unroll
    for (int j = 0; j < HM; j++) {
        float a = b1[j];
        #pragma unroll
        for (int i = 0; i < HM; i++) a = fmaf(h[i], W1[i * HM + j], a);
        h2[j] = fmaxf(a, 0.f);
    }
    #pragma unroll
    for (int j = 0; j < HM; j++) {
        float a = b2[j];
        #pragma unroll
        for (int i = 0; i < HM; i++) a = fmaf(h2[i], W2[i * HM + j], a);
        h[j] = fmaxf(a, 0.f);
    }
    float l0 = b3[0], l1 = b3[1];
    #pragma unroll
    for (int i = 0; i < HM; i++) {
        l0 = fmaf(h[i], W3[i * 2 + 0], l0);
        l1 = fmaf(h[i], W3[i * 2 + 1], l1);
    }
    const float2 g2 = ((const float2*)gum)[e];
    float v0 = l0 + g2.x, v1 = l1 + g2.y;
    float ew = 0.f;
    if (!(v1 > v0)) {
        const float2 ee2 = ((const float2*)ee)[e];
        float z = fmaf(ee2.x, Wl[0], bl[0]);
        ew = ee2.y / (1.f + __expf(-z));
    }
    ew_out[e] = ew;
    if (ew != 0.f) atomicAdd(&deg[t], ew);
}

__global__ __launch_bounds__(256) void node_pre_kernel(
    const float* __restrict__ x, const float* __restrict__ token,
    const float* __restrict__ Wc, const float* __restrict__ deg,
    float* __restrict__ xw, float* __restrict__ dis)
{
    int n = blockIdx.x * 256 + threadIdx.x;
    if (n >= NN) return;
    float xa[6];
    xa[0] = x[n];
    #pragma unroll
    for (int i = 0; i < 5; i++) xa[1 + i] = token[n * 5 + i];
    #pragma unroll
    for (int k = 0; k < HG; k++) {
        float a = 0.f;
        #pragma unroll
        for (int i = 0; i < 6; i++) a = fmaf(xa[i], Wc[i * HG + k], a);
        xw[n * HG + k] = a;
    }
    dis[n] = rsqrtf(deg[n] + 1.0f);
}

__global__ __launch_bounds__(256) void edge_scatter_kernel(
    const int* __restrict__ eidx, const float* __restrict__ ew,
    const float* __restrict__ dis, const float* __restrict__ xw,
    float* __restrict__ agg)
{
    int e = blockIdx.x * 256 + threadIdx.x;
    if (e >= NE) return;
    float w = ew[e];
    if (w == 0.f) return;
    int s = eidx[e];
    int t = eidx[NE + e];
    float norm = dis[s] * w * dis[t];
    #pragma unroll
    for (int k = 0; k < HG; k++)
        atomicAdd(&agg[t * HG + k], norm * xw[s * HG + k]);
}

__global__ __launch_bounds__(256) void node_out_kernel(
    const float* __restrict__ agg, const float* __restrict__ xw,
    const float* __restrict__ dis, const float* __restrict__ bc,
    const float* __restrict__ Wo, const float* __restrict__ bo,
    float* __restrict__ out)
{
    int n = blockIdx.x * 256 + threadIdx.x;
    if (n >= NN) return;
    float d = dis[n];
    float self = d * d;
    float acc = bo[0];
    #pragma unroll
    for (int k = 0; k < HG; k++) {
        float v = agg[n * HG + k] + xw[n * HG + k] * self + bc[k];
        acc = fmaf(v, Wo[k], acc);
    }
    out[n] = 1.f / (1.f + __expf(-acc));
}

extern "C" void kernel_launch(void* const* d_in, const int* in_sizes, int n_in,
                              void* d_out, int out_size, void* d_ws, size_t ws_size,
                              hipStream_t stream) {
    const float* x   = (const float*)d_in[0];
    const float* tok = (const float*)d_in[1];
    const float* eg  = (const float*)d_in[2];
    const float* ee  = (const float*)d_in[3];
    const float* gum = (const float*)d_in[4];
    const int*   ei  = (const int*)d_in[5];
    const float* W0  = (const float*)d_in[6];
    const float* b0  = (const float*)d_in[7];
    const float* W1  = (const float*)d_in[8];
    const float* b1  = (const float*)d_in[9];
    const float* W2  = (const float*)d_in[10];
    const float* b2  = (const float*)d_in[11];
    const float* W3  = (const float*)d_in[12];
    const float* b3  = (const float*)d_in[13];
    const float* Wl  = (const float*)d_in[14];
    const float* bl  = (const float*)d_in[15];
    const float* Wc  = (const float*)d_in[16];
    const float* bc  = (const float*)d_in[17];
    const float* Wo  = (const float*)d_in[18];
    const float* bo  = (const float*)d_in[19];
    float* out = (float*)d_out;

    dim3 blk(256);
    dim3 mgrid(NE / 64);                // 64 edges/block (4 waves x 16): 50000
    dim3 rgrid(RCAP / 256);             // 256 blocks
    dim3 egrid(NE / 256);               // fallback
    dim3 ngrid((NN + 255) / 256);

    // ws layout (float offsets); total ~30.4 MB <= proven 30.8 MB budget
    size_t off_xall8  = 0;                                  // NN*8
    size_t off_z      = off_xall8 + (size_t)NN * 8;         // NN*12
    size_t off_sw     = off_z + (size_t)NN * 12;            // NN*MAXK float
    size_t off_ss     = off_sw + (size_t)NN * MAXK;         // NN*MAXK int
    size_t off_cnt    = off_ss + (size_t)NN * MAXK;         // NN int
    size_t off_novf   = off_cnt + NN;                       // 1 int
    size_t off_ncheck = off_novf + 1;                       // 1 int
    size_t off_dis    = off_ncheck + 1;                     // NN
    size_t off_ohead  = off_dis + NN;                       // NN int
    size_t off_ovfw   = off_ohead + NN;                     // OVF_CAP
    size_t off_ovfs   = off_ovfw + OVF_CAP;                 // OVF_CAP int
    size_t off_onxt   = off_ovfs + OVF_CAP;                 // OVF_CAP int
    size_t off_rid    = off_onxt + OVF_CAP;                 // RCAP int
    size_t need_new   = (off_rid + RCAP) * sizeof(float);

    if (ws_size >= need_new) {
        float*  ws      = (float*)d_ws;
        float*  xall8   = ws + off_xall8;
        float*  z       = ws + off_z;
        float*  slots_w = ws + off_sw;
        int*    slots_s = (int*)(ws + off_ss);
        int*    cnt     = (int*)(ws + off_cnt);
        int*    novf    = (int*)(ws + off_novf);
        int*    ncheck  = (int*)(ws + off_ncheck);
        float*  dis     = ws + off_dis;
        int*    ohead   = (int*)(ws + off_ohead);
        float*  ovf_w   = ws + off_ovfw;
        int*    ovf_s   = (int*)(ws + off_ovfs);
        int*    onxt    = (int*)(ws + off_onxt);
        int*    rid     = (int*)(ws + off_rid);

        hipMemsetAsync(cnt, 0, (size_t)(NN + 2) * sizeof(int), stream);  // cnt+novf+ncheck
        hipMemsetAsync(ohead, 0xFF, (size_t)NN * sizeof(int), stream);   // ohead = -1

        pack_kernel<<<ngrid, blk, 0, stream>>>(x, tok, Wc, xall8, z);
        edge_mfma_kernel<<<mgrid, blk, 0, stream>>>(xall8, eg, ee, gum, ei,
                                                    W0, b0, W1, b1, W2, b2, W3, b3,
                                                    Wl, bl, slots_w, slots_s, cnt,
                                                    ohead, onxt, ovf_w, ovf_s, novf,
                                                    rid, ncheck);
        recheck_kernel<<<rgrid, blk, 0, stream>>>(xall8, eg, ee, gum, ei,
                                                  W0, b0, W1, b1, W2, b2, W3, b3,
                                                  Wl, bl, slots_w, slots_s, cnt,
                                                  ohead, onxt, ovf_w, ovf_s, novf,
                                                  rid, ncheck);
        node_deg_kernel<<<ngrid, blk, 0, stream>>>(slots_w, cnt, ohead, onxt, ovf_w,
                                                   z, dis);
        gather_out2_kernel<<<ngrid, blk, 0, stream>>>(slots_w, slots_s, cnt,
                                                      ohead, onxt, ovf_w, ovf_s,
                                                      z, dis, bc, Wo, bo, out);
    } else {
        // Fallback: Round-1 scatter layout
        float* ws  = (float*)d_ws;
        float* ew  = ws;
        float* deg = ew + NE;
        float* agg = deg + NN;
        float* xw  = agg + (size_t)NN * HG;
        float* dis = xw + (size_t)NN * HG;

        hipMemsetAsync(deg, 0, (size_t)(NN + (size_t)NN * HG) * sizeof(float), stream);
        edge_mlp_kernel<<<egrid, blk, 0, stream>>>(x, tok, eg, ee, gum, ei,
                                                   W0, b0, W1, b1, W2, b2, W3, b3,
                                                   Wl, bl, ew, deg);
        node_pre_kernel<<<ngrid, blk, 0, stream>>>(x, tok, Wc, deg, xw, dis);
        edge_scatter_kernel<<<egrid, blk, 0, stream>>>(ei, ew, dis, xw, agg);
        node_out_kernel<<<ngrid, blk, 0, stream>>>(agg, xw, dis, bc, Wo, bo, out);
    }
}